// Round 1
// baseline (70.640 us; speedup 1.0000x reference)
//
#include <hip/hip_runtime.h>

#define BLK 256
#define NV 7

// Masked (check,var) entries of H, flattened:
//   c0: v {0,2,4,6}  -> idx 0..3
//   c1: v {1,2,5,6}  -> idx 4..7
//   c2: v {3,4,5,6}  -> idx 8..11
__device__ __constant__ int kVidx[12] = {0,2,4,6, 1,2,5,6, 3,4,5,6};

static __device__ __forceinline__ float frcp(float x) {
    return __builtin_amdgcn_rcpf(x);
}

// One BP iteration over the 12 masked messages.
// l[7]: channel LLRs; m[12]: c2v messages in/out; total[7]: out.
static __device__ __forceinline__ void bp_body(const float l[NV], float m[12], float total[NV]) {
    float t[12];
#pragma unroll
    for (int i = 0; i < 12; ++i) {
        // tanh(x/2) = (e^x - 1) / (e^x + 1)
        float e = __expf(l[kVidx[i]] + m[i]);
        t[i] = (e - 1.0f) * frcp(e + 1.0f);
    }
    float p0 = (t[0] * t[1]) * (t[2] * t[3]);
    float p1 = (t[4] * t[5]) * (t[6] * t[7]);
    float p2 = (t[8] * t[9]) * (t[10] * t[11]);

    float mn[12];
#pragma unroll
    for (int i = 0; i < 4; ++i)  mn[i] = p0 * frcp(t[i] + 1e-10f);
#pragma unroll
    for (int i = 4; i < 8; ++i)  mn[i] = p1 * frcp(t[i] + 1e-10f);
#pragma unroll
    for (int i = 8; i < 12; ++i) mn[i] = p2 * frcp(t[i] + 1e-10f);

    // total[v] = llr[v] + sum_c m_new[c][v]; unmasked m_new == phi(1.0) ~= 1.0
    total[0] = l[0] + mn[0] + 2.0f;
    total[1] = l[1] + mn[4] + 2.0f;
    total[2] = l[2] + (mn[1] + mn[5]) + 1.0f;
    total[3] = l[3] + mn[8] + 2.0f;
    total[4] = l[4] + (mn[2] + mn[9]) + 1.0f;
    total[5] = l[5] + (mn[6] + mn[10]) + 1.0f;
    total[6] = l[6] + (mn[3] + mn[7]) + mn[11];

#pragma unroll
    for (int i = 0; i < 12; ++i) m[i] = total[kVidx[i]] - mn[i];
}

template <int ITERS>
static __device__ __forceinline__ void bp_fixed(const float l[NV], float o[NV]) {
    float m[12];
    float total[NV];
#pragma unroll
    for (int i = 0; i < 12; ++i) m[i] = 0.0f;
#pragma unroll
    for (int it = 0; it < ITERS; ++it) bp_body(l, m, total);
    // out = llr + sum_c m_v2c = llr + 3*total - (total - llr) = 2*(llr + total)
#pragma unroll
    for (int v = 0; v < NV; ++v) o[v] = 2.0f * (l[v] + total[v]);
}

static __device__ __forceinline__ void bp_dyn(int iters, const float l[NV], float o[NV]) {
    if (iters <= 0) {
#pragma unroll
        for (int v = 0; v < NV; ++v) o[v] = l[v];
        return;
    }
    float m[12];
    float total[NV];
#pragma unroll
    for (int i = 0; i < 12; ++i) m[i] = 0.0f;
    for (int it = 0; it < iters; ++it) bp_body(l, m, total);
#pragma unroll
    for (int v = 0; v < NV; ++v) o[v] = 2.0f * (l[v] + total[v]);
}

__global__ __launch_bounds__(BLK) void ldpc_bp_kernel(const float* __restrict__ llr,
                                                      const int* __restrict__ max_iters,
                                                      float* __restrict__ out, int B) {
    __shared__ float lds[BLK * NV];  // 1792 floats = 7168 B
    const int tid = threadIdx.x;
    const int block0 = blockIdx.x * BLK;
    const bool full = (block0 + BLK) <= B;

    float l[NV];
    if (full) {
        // Vectorized stage-in: 448 float4 per block, fully coalesced.
        const float4* g4 = (const float4*)(llr + (size_t)block0 * NV);
        float4* l4 = (float4*)lds;
        l4[tid] = g4[tid];
        if (tid < (BLK * NV / 4 - BLK)) l4[tid + BLK] = g4[tid + BLK];
        __syncthreads();
#pragma unroll
        for (int v = 0; v < NV; ++v) l[v] = lds[tid * NV + v];  // stride 7: 2-way bank alias, free
    } else {
        const int b = block0 + tid;
#pragma unroll
        for (int v = 0; v < NV; ++v) l[v] = (b < B) ? llr[(size_t)b * NV + v] : 0.0f;
        __syncthreads();  // keep barrier count uniform with the other path's stores? (not needed: barrier is per-block, and path choice is block-uniform)
    }

    float o[NV];
    const int n = *max_iters;
    if (n == 5) bp_fixed<5>(l, o);
    else bp_dyn(n, l, o);

    if (full) {
        __syncthreads();
#pragma unroll
        for (int v = 0; v < NV; ++v) lds[tid * NV + v] = o[v];
        __syncthreads();
        float4* g4 = (float4*)(out + (size_t)block0 * NV);
        const float4* l4 = (const float4*)lds;
        g4[tid] = l4[tid];
        if (tid < (BLK * NV / 4 - BLK)) g4[tid + BLK] = l4[tid + BLK];
    } else {
        const int b = block0 + tid;
        if (b < B) {
#pragma unroll
            for (int v = 0; v < NV; ++v) out[(size_t)b * NV + v] = o[v];
        }
    }
}

extern "C" void kernel_launch(void* const* d_in, const int* in_sizes, int n_in,
                              void* d_out, int out_size, void* d_ws, size_t ws_size,
                              hipStream_t stream) {
    const float* llr = (const float*)d_in[0];
    const int* max_iters = (const int*)d_in[1];
    float* out = (float*)d_out;
    const int B = in_sizes[0] / NV;
    const int blocks = (B + BLK - 1) / BLK;
    ldpc_bp_kernel<<<blocks, BLK, 0, stream>>>(llr, max_iters, out, B);
}

// Round 3
// 69.396 us; speedup vs baseline: 1.0179x; 1.0179x over previous
//
#include <hip/hip_runtime.h>

#define BLK 256
#define NV 7

// Masked (check,var) entries of H, flattened:
//   c0: v {0,2,4,6}  -> idx 0..3
//   c1: v {1,2,5,6}  -> idx 4..7
//   c2: v {3,4,5,6}  -> idx 8..11
__device__ __constant__ int kVidx[12] = {0,2,4,6, 1,2,5,6, 3,4,5,6};

static __device__ __forceinline__ float frcp(float x) {
    return __builtin_amdgcn_rcpf(x);
}

// One BP iteration over the 12 masked edges.
// l[7]: channel LLRs. x[12]: per-edge (llr + m_c2v), in/out. s[7]: out, = l + total.
// phi(y) = 2*atanh(tanh(y/2)) is the identity; leave-one-out products replace
// the eps-guarded division prod/(t+1e-10) (exact to ~1e-10 relative).
static __device__ __forceinline__ void bp_body(const float l[NV], float x[12], float s[NV]) {
    float t[12];
#pragma unroll
    for (int i = 0; i < 12; ++i) {
        // tanh(x/2) = (e^x - 1) / (e^x + 1)
        float e = __expf(x[i]);
        t[i] = (e - 1.0f) * frcp(e + 1.0f);
    }

    // Leave-one-out products per check node (degree 4): pure muls, no rcp.
    float mn[12];
#pragma unroll
    for (int c = 0; c < 3; ++c) {
        const int b = 4 * c;
        const float pab = t[b + 0] * t[b + 1];
        const float pcd = t[b + 2] * t[b + 3];
        mn[b + 0] = t[b + 1] * pcd;
        mn[b + 1] = t[b + 0] * pcd;
        mn[b + 2] = pab * t[b + 3];
        mn[b + 3] = pab * t[b + 2];
    }

    // s[v] = l[v] + total[v];  total[v] = l[v] + sum_c m_new[c][v], with
    // unmasked m_new == phi(1.0) == 1.0 folded into the constants.
    s[0] = 2.0f * l[0] + mn[0] + 2.0f;
    s[1] = 2.0f * l[1] + mn[4] + 2.0f;
    s[2] = 2.0f * l[2] + (mn[1] + mn[5]) + 1.0f;
    s[3] = 2.0f * l[3] + mn[8] + 2.0f;
    s[4] = 2.0f * l[4] + (mn[2] + mn[9]) + 1.0f;
    s[5] = 2.0f * l[5] + (mn[6] + mn[10]) + 1.0f;
    s[6] = 2.0f * l[6] + (mn[3] + mn[7]) + mn[11];

    // x_next = l + m_v2c = l + (total - mn) = s - mn
#pragma unroll
    for (int i = 0; i < 12; ++i) x[i] = s[kVidx[i]] - mn[i];
}

template <int ITERS>
static __device__ __forceinline__ void bp_fixed(const float l[NV], float o[NV]) {
    float x[12], s[NV];
#pragma unroll
    for (int i = 0; i < 12; ++i) x[i] = l[kVidx[i]];
#pragma unroll
    for (int it = 0; it < ITERS; ++it) bp_body(l, x, s);
    // out = llr + sum_c m_v2c = 2*(llr + total) = 2*s
#pragma unroll
    for (int v = 0; v < NV; ++v) o[v] = 2.0f * s[v];
}

static __device__ __forceinline__ void bp_dyn(int iters, const float l[NV], float o[NV]) {
    if (iters <= 0) {
#pragma unroll
        for (int v = 0; v < NV; ++v) o[v] = l[v];
        return;
    }
    float x[12], s[NV];
#pragma unroll
    for (int i = 0; i < 12; ++i) x[i] = l[kVidx[i]];
    for (int it = 0; it < iters; ++it) bp_body(l, x, s);
#pragma unroll
    for (int v = 0; v < NV; ++v) o[v] = 2.0f * s[v];
}

__global__ __launch_bounds__(BLK) void ldpc_bp_kernel(const float* __restrict__ llr,
                                                      const int* __restrict__ max_iters,
                                                      float* __restrict__ out, int B) {
    __shared__ float lds[BLK * NV];  // 7168 B
    const int tid = threadIdx.x;
    const int block0 = blockIdx.x * BLK;
    const bool full = (block0 + BLK) <= B;

    float l[NV];
    if (full) {
        // Vectorized stage-in: 448 float4 per block, fully coalesced.
        const float4* g4 = (const float4*)(llr + (size_t)block0 * NV);
        float4* l4 = (float4*)lds;
        l4[tid] = g4[tid];
        if (tid < (BLK * NV / 4 - BLK)) l4[tid + BLK] = g4[tid + BLK];
        __syncthreads();
#pragma unroll
        for (int v = 0; v < NV; ++v) l[v] = lds[tid * NV + v];  // stride 7: 2 lanes/bank, free
    } else {
        const int b = block0 + tid;
#pragma unroll
        for (int v = 0; v < NV; ++v) l[v] = (b < B) ? llr[(size_t)b * NV + v] : 0.0f;
    }

    float o[NV];
    const int n = *max_iters;
    if (n == 5) bp_fixed<5>(l, o);
    else bp_dyn(n, l, o);

    if (full) {
        __syncthreads();
#pragma unroll
        for (int v = 0; v < NV; ++v) lds[tid * NV + v] = o[v];
        __syncthreads();
        float4* g4 = (float4*)(out + (size_t)block0 * NV);
        const float4* l4 = (const float4*)lds;
        g4[tid] = l4[tid];
        if (tid < (BLK * NV / 4 - BLK)) g4[tid + BLK] = l4[tid + BLK];
    } else {
        const int b = block0 + tid;
        if (b < B) {
#pragma unroll
            for (int v = 0; v < NV; ++v) out[(size_t)b * NV + v] = o[v];
        }
    }
}

extern "C" void kernel_launch(void* const* d_in, const int* in_sizes, int n_in,
                              void* d_out, int out_size, void* d_ws, size_t ws_size,
                              hipStream_t stream) {
    const float* llr = (const float*)d_in[0];
    const int* max_iters = (const int*)d_in[1];
    float* out = (float*)d_out;
    const int B = in_sizes[0] / NV;
    const int blocks = (B + BLK - 1) / BLK;
    ldpc_bp_kernel<<<blocks, BLK, 0, stream>>>(llr, max_iters, out, B);
}